// Round 10
// baseline (131.574 us; speedup 1.0000x reference)
//
#include <hip/hip_runtime.h>

// SIR recurrence, R8 (resubmitted unchanged — R9 bench was a GPU-acquisition
// timeout, no data). Cut STORE COUNT, not chain depth.
// Model re-fit (R1-R7 + m07's dep-fma ~4cyc): solo-lane dword stores cost
// ~10cyc each (issue/drain), dep chain only ~12cyc -> R5's 54cyc/step was
// ~75% store cost. R6/R7 "chain shortening" attacked the wrong term.
// Fix: batch 4 steps -> emit 20 output floats (col-4 zeros INCLUDED) as
// 5 aligned global_store_dwordx4. 16 scattered dwords -> 5 wide stores
// per 4 steps; helper threads are gone (zeros ride in the packed quads).
//
// FP ops bit-identical to R6/R7 (absmax == 0.0 proven on HW):
//   f = fma(gamma,v,L); g = fma(-gamma,u,1)
//   u' = fma(u,f,delta); v' = fma(v,g,-delta)
//   s1' = fma(w2sq,u,s1); s3' = fma(w4sq,u,s3)
// Output row k (after step k): {u_{k+1}, s1_{k+1}, v_{k+1}, s3_{k+1}, 0}

__global__ __launch_bounds__(64) void sir_kernel(
    const float* __restrict__ x, const float* __restrict__ w2p,
    const float* __restrict__ w3p, const float* __restrict__ b3p,
    const float* __restrict__ w4p, const int* __restrict__ np,
    float* __restrict__ out) {
  if (threadIdx.x != 0) return;  // truly solo wave; lane 0 does everything

  const int n = *np;
  const int rows = n - 1;

  const float w2 = *w2p, w3 = *w3p, b3 = *b3p, w4 = *w4p;
  const float w2sq   = w2 * w2;
  const float w4sq   = w4 * w4;
  const float L      = 1.0f - w2sq - w4sq;
  const float gamma  = (w3 * w3) / 1000.0f;
  const float mgamma = -gamma;
  const float delta  = fmaf(w3, b3, b3);
  const float mdelta = -delta;

  float u = x[0], s1 = x[1], v = x[2], s3 = x[3];

  if (rows == 2047) {
    float4* __restrict__ q = (float4*)out;  // d_out is >=256B aligned
#pragma unroll 1
    for (int b = 0; b < 511; ++b) {  // 511 blocks x 4 steps = rows 0..2043
      // step 1
      const float f1  = fmaf(gamma, v, L);
      const float g1  = fmaf(mgamma, u, 1.0f);
      const float s11 = fmaf(w2sq, u, s1);
      const float s31 = fmaf(w4sq, u, s3);
      const float u1  = fmaf(u, f1, delta);
      const float v1  = fmaf(v, g1, mdelta);
      // step 2
      const float f2  = fmaf(gamma, v1, L);
      const float g2  = fmaf(mgamma, u1, 1.0f);
      const float s12 = fmaf(w2sq, u1, s11);
      const float s32 = fmaf(w4sq, u1, s31);
      const float u2  = fmaf(u1, f2, delta);
      const float v2  = fmaf(v1, g2, mdelta);
      // step 3
      const float f3  = fmaf(gamma, v2, L);
      const float g3  = fmaf(mgamma, u2, 1.0f);
      const float s13 = fmaf(w2sq, u2, s12);
      const float s33 = fmaf(w4sq, u2, s32);
      const float u3  = fmaf(u2, f3, delta);
      const float v3  = fmaf(v2, g3, mdelta);
      // step 4
      const float f4  = fmaf(gamma, v3, L);
      const float g4  = fmaf(mgamma, u3, 1.0f);
      const float s14 = fmaf(w2sq, u3, s13);
      const float s34 = fmaf(w4sq, u3, s33);
      const float u4  = fmaf(u3, f4, delta);
      const float v4  = fmaf(v3, g4, mdelta);
      // 4 rows = 20 floats = 5 aligned dwordx4 (zeros included)
      q[0] = make_float4(u1, s11, v1, s31);
      q[1] = make_float4(0.0f, u2, s12, v2);
      q[2] = make_float4(s32, 0.0f, u3, s13);
      q[3] = make_float4(v3, s33, 0.0f, u4);
      q[4] = make_float4(s14, v4, s34, 0.0f);
      q += 5;
      u = u4; v = v4; s1 = s14; s3 = s34;
    }
    // tail: rows 2044..2046, scalar (col-4 zero written here too)
    float* __restrict__ p = (float*)q;
    for (int i = 0; i < 3; ++i) {
      const float f = fmaf(gamma, v, L);
      const float g = fmaf(mgamma, u, 1.0f);
      s1 = fmaf(w2sq, u, s1);
      s3 = fmaf(w4sq, u, s3);
      u = fmaf(u, f, delta);
      v = fmaf(v, g, mdelta);
      p[0] = u; p[1] = s1; p[2] = v; p[3] = s3; p[4] = 0.0f;
      p += 5;
    }
  } else {
    // generic fallback, same FP sequence, scalar stores
    float* __restrict__ p = out;
#pragma unroll 4
    for (int i = 0; i < rows; ++i) {
      const float f = fmaf(gamma, v, L);
      const float g = fmaf(mgamma, u, 1.0f);
      s1 = fmaf(w2sq, u, s1);
      s3 = fmaf(w4sq, u, s3);
      u = fmaf(u, f, delta);
      v = fmaf(v, g, mdelta);
      p[0] = u; p[1] = s1; p[2] = v; p[3] = s3; p[4] = 0.0f;
      p += 5;
    }
  }
}

extern "C" void kernel_launch(void* const* d_in, const int* in_sizes, int n_in,
                              void* d_out, int out_size, void* d_ws, size_t ws_size,
                              hipStream_t stream) {
  const float* x   = (const float*)d_in[0];
  const float* w2  = (const float*)d_in[1];
  const float* w3  = (const float*)d_in[2];
  const float* b3  = (const float*)d_in[3];
  const float* w4  = (const float*)d_in[4];
  const int*   n   = (const int*)d_in[5];
  float* out = (float*)d_out;
  sir_kernel<<<1, 64, 0, stream>>>(x, w2, w3, b3, w4, n, out);
}

// Round 11
// 106.398 us; speedup vs baseline: 1.2366x; 1.2366x over previous
//
#include <hip/hip_runtime.h>

// SIR recurrence, R9: ZERO memory ops in the serial loop.
// R1-R8 re-fit: every variant kept stores in the loop; vmcnt-before-VGPR-
// reuse + solo-lane VMEM issue costs confound everything (R8: recycling 20
// store VGPRs each iter -> lockstep with store COMPLETION -> 96 cyc/step).
// New structure: all 64 lanes run the recurrence redundantly (lane-invariant
// wave64 VALU, same cost as 1 lane); step j parks {u,s1,v,s3} into lane
// (j&63)'s registers via v_cmp_eq(inline const)+4 v_cndmask after full-64
// unroll. Every 64 steps one wave-wide flush: 5 scattered dword stores
// cover 64 rows x 5 cols (col-4 zeros included) = 0.08 stores/step, and
// flush data regs are idle for the next ~64 steps (no vmcnt coupling).
// Serial body: 6 fma + 5 select = 11 VALU, 0 VMEM/LDS.
//
// FP ops bit-identical to R6/R7/R8 (absmax == 0.0 proven on HW):
//   f = fma(gamma,v,L); g = fma(-gamma,u,1)
//   u' = fma(u,f,delta); v' = fma(v,g,-delta)
//   s1' = fma(w2sq,u,s1); s3' = fma(w4sq,u,s3)
// Row k (k=0..2046) = state after step k+1. Block b parks steps
// [64b, 64b+63] into lanes 0..63 -> rows 64b..64b+63; block 31 runs a
// 2048th step (parked, never stored) and flushes lanes 0..62 only.

__global__ __launch_bounds__(64) void sir_kernel(
    const float* __restrict__ x, const float* __restrict__ w2p,
    const float* __restrict__ w3p, const float* __restrict__ b3p,
    const float* __restrict__ w4p, const int* __restrict__ np,
    float* __restrict__ out) {
  const int lane = threadIdx.x;  // one wave of 64
  const int n = *np;
  const int rows = n - 1;

  const float w2 = *w2p, w3 = *w3p, b3 = *b3p, w4 = *w4p;
  const float w2sq   = w2 * w2;
  const float w4sq   = w4 * w4;
  const float L      = 1.0f - w2sq - w4sq;
  const float gamma  = (w3 * w3) / 1000.0f;
  const float mgamma = -gamma;
  const float delta  = fmaf(w3, b3, b3);
  const float mdelta = -delta;

  // all lanes hold identical state (redundant compute)
  float u = x[0], s1 = x[1], v = x[2], s3 = x[3];

  if (rows == 2047) {
    float pu = 0.0f, ps1 = 0.0f, pv = 0.0f, ps3 = 0.0f;  // parked row
    float* __restrict__ o = out + 5 * lane;
#pragma unroll 1
    for (int b = 0; b < 32; ++b) {
#pragma unroll
      for (int j = 0; j < 64; ++j) {
        const float f   = fmaf(gamma, v, L);
        const float g   = fmaf(mgamma, u, 1.0f);
        const float ns1 = fmaf(w2sq, u, s1);
        const float ns3 = fmaf(w4sq, u, s3);
        const float nu  = fmaf(u, f, delta);
        const float nv  = fmaf(v, g, mdelta);
        u = nu; v = nv; s1 = ns1; s3 = ns3;
        const bool park = (lane == j);  // j is a literal after unroll
        pu  = park ? nu  : pu;
        ps1 = park ? ns1 : ps1;
        pv  = park ? nv  : pv;
        ps3 = park ? ns3 : ps3;
      }
      // wave-wide flush: 64 rows x 5 cols in 5 store instructions
      if (b < 31 || lane < 63) {  // block 31: row 2047 doesn't exist
        o[0] = pu;
        o[1] = ps1;
        o[2] = pv;
        o[3] = ps3;
        o[4] = 0.0f;  // col-4 zeros ride along (d_out re-poisoned 0xAA)
      }
      o += 5 * 64;
    }
  } else {
    // generic fallback: lane-0 scalar loop, same FP sequence
    if (lane == 0) {
      float* __restrict__ p = out;
#pragma unroll 4
      for (int i = 0; i < rows; ++i) {
        const float f = fmaf(gamma, v, L);
        const float g = fmaf(mgamma, u, 1.0f);
        s1 = fmaf(w2sq, u, s1);
        s3 = fmaf(w4sq, u, s3);
        u = fmaf(u, f, delta);
        v = fmaf(v, g, mdelta);
        p[0] = u; p[1] = s1; p[2] = v; p[3] = s3; p[4] = 0.0f;
        p += 5;
      }
    }
  }
}

extern "C" void kernel_launch(void* const* d_in, const int* in_sizes, int n_in,
                              void* d_out, int out_size, void* d_ws, size_t ws_size,
                              hipStream_t stream) {
  const float* x   = (const float*)d_in[0];
  const float* w2  = (const float*)d_in[1];
  const float* w3  = (const float*)d_in[2];
  const float* b3  = (const float*)d_in[3];
  const float* w4  = (const float*)d_in[4];
  const int*   n   = (const int*)d_in[5];
  float* out = (float*)d_out;
  sir_kernel<<<1, 64, 0, stream>>>(x, w2, w3, b3, w4, n, out);
}

// Round 12
// 97.877 us; speedup vs baseline: 1.3443x; 1.0871x over previous
//
#include <hip/hip_runtime.h>

// SIR recurrence, R10: minimize serial-loop INSTRUCTION COUNT.
// R9 proved the law: solo wave issues ~1 instr/5cyc regardless of deps or
// type (R1/R5 10.5 instr=53cyc; R9 11 instr=54.5cyc, zero VMEM). So: park
// only {u,v} per step (cmp + 2 cndmask); s1/s3 are linear in prefix-sums of
// u -> recovered per 64-step block via one DPP wave-scan (pure VALU, no LDS)
// at flush time. Serial body: 4 fma + cmp + 2 cndmask = 7 instr/step.
// Park/store regs alternate A/B across blocks so store-data VGPRs are never
// recycled while stores are in flight (R8's vmcnt trap).
//
// Cols 0/2 (u,v): bit-identical FP ops to R6-R9 (absmax 0.0 proven x4).
// Cols 1/3 (s1,s3): s1_row = fma(w2sq, T_row, s1_0), T = cumulative sum of
// pre-step u; scan-reassociated vs reference's serial fma chain -> expected
// absmax ~1e-6..1e-4 (accepted gamble; revert to R9 parking if it fails).

template <int CTRL, int RMASK>
__device__ __forceinline__ float dpp0(float x) {
  // update_dpp with old=0, bound_ctrl=false: disabled/invalid lanes yield 0
  return __int_as_float(__builtin_amdgcn_update_dpp(
      0, __float_as_int(x), CTRL, RMASK, 0xf, false));
}

// canonical GCN wave64 inclusive prefix-sum (rocPRIM pattern): 6 DPP adds
__device__ __forceinline__ float wave_incl_scan(float x) {
  x += dpp0<0x111, 0xf>(x);  // row_shr:1
  x += dpp0<0x112, 0xf>(x);  // row_shr:2
  x += dpp0<0x114, 0xf>(x);  // row_shr:4
  x += dpp0<0x118, 0xf>(x);  // row_shr:8
  x += dpp0<0x142, 0xa>(x);  // row_bcast:15 -> rows 1,3
  x += dpp0<0x143, 0xc>(x);  // row_bcast:31 -> rows 2,3
  return x;
}

__global__ __launch_bounds__(64) void sir_kernel(
    const float* __restrict__ x, const float* __restrict__ w2p,
    const float* __restrict__ w3p, const float* __restrict__ b3p,
    const float* __restrict__ w4p, const int* __restrict__ np,
    float* __restrict__ out) {
  const int lane = threadIdx.x;  // single wave of 64
  const int n = *np;
  const int rows = n - 1;

  const float w2 = *w2p, w3 = *w3p, b3 = *b3p, w4 = *w4p;
  const float w2sq   = w2 * w2;
  const float w4sq   = w4 * w4;
  const float L      = 1.0f - w2sq - w4sq;
  const float gamma  = (w3 * w3) / 1000.0f;
  const float mgamma = -gamma;
  const float delta  = fmaf(w3, b3, b3);
  const float mdelta = -delta;

  float u = x[0], v = x[2];           // lane-invariant live state
  const float s1_0 = x[1], s3_0 = x[3];

  if (rows == 2047) {
    float G = u;  // cumulative pre-step u over all completed rows (+u_0)
    float puA = 0.f, pvA = 0.f, puB = 0.f, pvB = 0.f;
    float* __restrict__ o = out + 5 * lane;

// one 64-step block: serial compute+park, then scan+flush
#define SIR_BLOCK(PU, PV, LAST)                                   \
  {                                                               \
    _Pragma("unroll")                                             \
    for (int j = 0; j < 64; ++j) {                                \
      const float f  = fmaf(gamma, v, L);                         \
      const float g  = fmaf(mgamma, u, 1.0f);                     \
      const float nu = fmaf(u, f, delta);                         \
      const float nv = fmaf(v, g, mdelta);                        \
      const bool park = (lane == j);                              \
      PU = park ? nu : PU;                                        \
      PV = park ? nv : PV;                                        \
      u = nu; v = nv;                                             \
    }                                                             \
    const float S   = wave_incl_scan(PU);                         \
    const float T   = (G + S) - PU; /* G + exclusive_scan */      \
    const float s1v = fmaf(w2sq, T, s1_0);                        \
    const float s3v = fmaf(w4sq, T, s3_0);                        \
    G += __shfl(S, 63);                                           \
    if (!(LAST) || lane < 63) { /* row 2047 doesn't exist */      \
      o[0] = PU; o[1] = s1v; o[2] = PV; o[3] = s3v; o[4] = 0.0f;  \
    }                                                             \
    o += 5 * 64;                                                  \
  }

#pragma unroll 1
    for (int bb = 0; bb < 16; ++bb) {      // 32 blocks as 16 A/B pairs
      SIR_BLOCK(puA, pvA, false)
      SIR_BLOCK(puB, pvB, bb == 15)
    }
#undef SIR_BLOCK
  } else {
    // generic fallback: lane-0 scalar loop, R6 FP sequence, all 5 cols
    if (lane == 0) {
      float s1 = s1_0, s3 = s3_0;
      float* __restrict__ p = out;
#pragma unroll 4
      for (int i = 0; i < rows; ++i) {
        const float f = fmaf(gamma, v, L);
        const float g = fmaf(mgamma, u, 1.0f);
        s1 = fmaf(w2sq, u, s1);
        s3 = fmaf(w4sq, u, s3);
        u = fmaf(u, f, delta);
        v = fmaf(v, g, mdelta);
        p[0] = u; p[1] = s1; p[2] = v; p[3] = s3; p[4] = 0.0f;
        p += 5;
      }
    }
  }
}

extern "C" void kernel_launch(void* const* d_in, const int* in_sizes, int n_in,
                              void* d_out, int out_size, void* d_ws, size_t ws_size,
                              hipStream_t stream) {
  const float* x   = (const float*)d_in[0];
  const float* w2  = (const float*)d_in[1];
  const float* w3  = (const float*)d_in[2];
  const float* b3  = (const float*)d_in[3];
  const float* w4  = (const float*)d_in[4];
  const int*   n   = (const int*)d_in[5];
  float* out = (float*)d_out;
  sir_kernel<<<1, 64, 0, stream>>>(x, w2, w3, b3, w4, n, out);
}

// Round 13
// 91.634 us; speedup vs baseline: 1.4359x; 1.0681x over previous
//
#include <hip/hip_runtime.h>

// SIR recurrence, R11: halve the serial-body FMA count with v_pk_fma_f32.
// Law from R1-R10: solo-wave time ~ emitted instr count x ~5-6.6cyc (deps,
// VMEM, type all secondary). R10 body = 7 instr (4 fma + cmp + 2 cndmask)
// = 46.2 cyc/step. This round: the step maps onto 2 VOP3P packed FMAs
// (bitwise-identical rounding per 32-bit half):
//   FG = pk_fma((γ,-γ), (u,v) op_sel-swapped, (L,1))  -> (f,g)
//   W  = pk_fma(W, FG, (δ,-δ))                        -> (nu,nv) in place
// Body = 2 pk_fma + cmp + 2 cndmask = 5 instr/step.
// Park/scan/flush machinery is R10's proven absmax==0.0 code, untouched:
// park (u,v) per step into lane j (A/B alternating regs), s1/s3 recovered
// per 64-block from one DPP inclusive scan of parked u.

typedef float f2 __attribute__((ext_vector_type(2)));

template <int CTRL, int RMASK>
__device__ __forceinline__ float dpp0(float x) {
  // update_dpp with old=0, bound_ctrl=false: disabled/invalid lanes yield 0
  return __int_as_float(__builtin_amdgcn_update_dpp(
      0, __float_as_int(x), CTRL, RMASK, 0xf, false));
}

// canonical GCN wave64 inclusive prefix-sum: 6 DPP adds
__device__ __forceinline__ float wave_incl_scan(float x) {
  x += dpp0<0x111, 0xf>(x);  // row_shr:1
  x += dpp0<0x112, 0xf>(x);  // row_shr:2
  x += dpp0<0x114, 0xf>(x);  // row_shr:4
  x += dpp0<0x118, 0xf>(x);  // row_shr:8
  x += dpp0<0x142, 0xa>(x);  // row_bcast:15 -> rows 1,3
  x += dpp0<0x143, 0xc>(x);  // row_bcast:31 -> rows 2,3
  return x;
}

__global__ __launch_bounds__(64) void sir_kernel(
    const float* __restrict__ x, const float* __restrict__ w2p,
    const float* __restrict__ w3p, const float* __restrict__ b3p,
    const float* __restrict__ w4p, const int* __restrict__ np,
    float* __restrict__ out) {
  const int lane = threadIdx.x;  // single wave of 64
  const int n = *np;
  const int rows = n - 1;

  const float w2 = *w2p, w3 = *w3p, b3 = *b3p, w4 = *w4p;
  const float w2sq   = w2 * w2;
  const float w4sq   = w4 * w4;
  const float L      = 1.0f - w2sq - w4sq;
  const float gamma  = (w3 * w3) / 1000.0f;
  const float delta  = fmaf(w3, b3, b3);

  const float s1_0 = x[1], s3_0 = x[3];

  if (rows == 2047) {
    f2 W;  W.x = x[0];  W.y = x[2];          // state pair (u, v)
    f2 C1; C1.x = gamma; C1.y = -gamma;      // (γ, -γ)
    f2 C2; C2.x = L;     C2.y = 1.0f;        // (L, 1)
    f2 C3; C3.x = delta; C3.y = -delta;      // (δ, -δ)

    float G = W.x;  // Σ pre-step u over completed steps (starts at u_0)
    float puA = 0.f, pvA = 0.f, puB = 0.f, pvB = 0.f;
    float* __restrict__ o = out + 5 * lane;

// one 64-step block: serial compute+park, then scan+flush (R10 logic)
#define SIR_BLOCK(PU, PV, LAST)                                          \
  {                                                                      \
    _Pragma("unroll")                                                    \
    for (int j = 0; j < 64; ++j) {                                       \
      f2 FG;                                                             \
      asm("v_pk_fma_f32 %0, %1, %2, %3 op_sel:[0,1,0] op_sel_hi:[1,0,1]" \
          : "=v"(FG)                                                     \
          : "v"(C1), "v"(W), "v"(C2));      /* (f,g) = (γv+L, -γu+1) */  \
      asm("v_pk_fma_f32 %0, %0, %1, %2"                                  \
          : "+v"(W)                                                      \
          : "v"(FG), "v"(C3));              /* (u,v) = (uf+δ, vg-δ) */   \
      const bool park = (lane == j);                                     \
      PU = park ? W.x : PU;                                              \
      PV = park ? W.y : PV;                                              \
    }                                                                    \
    const float S   = wave_incl_scan(PU);                                \
    const float T   = (G + S) - PU; /* G + exclusive_scan */             \
    const float s1v = fmaf(w2sq, T, s1_0);                               \
    const float s3v = fmaf(w4sq, T, s3_0);                               \
    G += __shfl(S, 63);                                                  \
    if (!(LAST) || lane < 63) { /* row 2047 doesn't exist */             \
      o[0] = PU; o[1] = s1v; o[2] = PV; o[3] = s3v; o[4] = 0.0f;         \
    }                                                                    \
    o += 5 * 64;                                                         \
  }

#pragma unroll 1
    for (int bb = 0; bb < 16; ++bb) {  // 32 blocks as 16 A/B pairs
      SIR_BLOCK(puA, pvA, false)
      SIR_BLOCK(puB, pvB, bb == 15)
    }
#undef SIR_BLOCK
  } else {
    // generic fallback: lane-0 scalar loop, proven FP sequence, all 5 cols
    if (lane == 0) {
      float u = x[0], v = x[2], s1 = s1_0, s3 = s3_0;
      const float mgamma = -gamma, mdelta = -delta;
      float* __restrict__ p = out;
#pragma unroll 4
      for (int i = 0; i < rows; ++i) {
        const float f = fmaf(gamma, v, L);
        const float g = fmaf(mgamma, u, 1.0f);
        s1 = fmaf(w2sq, u, s1);
        s3 = fmaf(w4sq, u, s3);
        u = fmaf(u, f, delta);
        v = fmaf(v, g, mdelta);
        p[0] = u; p[1] = s1; p[2] = v; p[3] = s3; p[4] = 0.0f;
        p += 5;
      }
    }
  }
}

extern "C" void kernel_launch(void* const* d_in, const int* in_sizes, int n_in,
                              void* d_out, int out_size, void* d_ws, size_t ws_size,
                              hipStream_t stream) {
  const float* x   = (const float*)d_in[0];
  const float* w2  = (const float*)d_in[1];
  const float* w3  = (const float*)d_in[2];
  const float* b3  = (const float*)d_in[3];
  const float* w4  = (const float*)d_in[4];
  const int*   n   = (const int*)d_in[5];
  float* out = (float*)d_out;
  sir_kernel<<<1, 64, 0, stream>>>(x, w2, w3, b3, w4, n, out);
}

// Round 14
// 80.088 us; speedup vs baseline: 1.6429x; 1.1442x over previous
//
#include <hip/hip_runtime.h>

// SIR recurrence, R12: park every 8th step; recover skipped rows in parallel.
// Law (R1-R11): solo-wave time ~ serial instr count x ~4-6.6cyc. R11 body =
// 2 pk_fma + 3 park = 5/step (~33us). This round parks only at steps ==0
// (mod 8) into lane j/8 -> serial = 2.375 instr/step. At block end (512
// steps), each lane re-applies 7 steps to its parked state (same pk_fma ops
// the serial phase executed -> bitwise-identical u/v), recovers s1/s3 from
// a DPP wave-scan of per-lane u-sums (same reassociation family proven
// absmax==0.0 in R10/R11), and stores its 8 contiguous rows (40 floats,
// 16B-aligned) as 10 dwordx4 (col-4 zeros packed in).
//
//   step: FG = pk_fma((γ,-γ),(u,v) op_sel-swapped,(L,1)); W = pk_fma(W,FG,(δ,-δ))
//   s1_row = fma(w2sq, T_row, s1_0), T_row = Σ_{t=0..row} u_t  (u_t pre-step)

typedef float f2 __attribute__((ext_vector_type(2)));

#define STEP(Wv, FGv)                                                    \
  asm("v_pk_fma_f32 %0, %1, %2, %3 op_sel:[0,1,0] op_sel_hi:[1,0,1]"     \
      : "=v"(FGv) : "v"(C1), "v"(Wv), "v"(C2));                          \
  asm("v_pk_fma_f32 %0, %0, %1, %2" : "+v"(Wv) : "v"(FGv), "v"(C3));

template <int CTRL, int RMASK>
__device__ __forceinline__ float dpp0(float x) {
  return __int_as_float(__builtin_amdgcn_update_dpp(
      0, __float_as_int(x), CTRL, RMASK, 0xf, false));
}

// canonical GCN wave64 inclusive prefix-sum: 6 DPP adds (proven R10/R11)
__device__ __forceinline__ float wave_incl_scan(float x) {
  x += dpp0<0x111, 0xf>(x);  // row_shr:1
  x += dpp0<0x112, 0xf>(x);  // row_shr:2
  x += dpp0<0x114, 0xf>(x);  // row_shr:4
  x += dpp0<0x118, 0xf>(x);  // row_shr:8
  x += dpp0<0x142, 0xa>(x);  // row_bcast:15 -> rows 1,3
  x += dpp0<0x143, 0xc>(x);  // row_bcast:31 -> rows 2,3
  return x;
}

__global__ __launch_bounds__(64) void sir_kernel(
    const float* __restrict__ x, const float* __restrict__ w2p,
    const float* __restrict__ w3p, const float* __restrict__ b3p,
    const float* __restrict__ w4p, const int* __restrict__ np,
    float* __restrict__ out) {
  const int lane = threadIdx.x;  // single wave of 64
  const int n = *np;
  const int rows = n - 1;

  const float w2 = *w2p, w3 = *w3p, b3 = *b3p, w4 = *w4p;
  const float w2sq  = w2 * w2;
  const float w4sq  = w4 * w4;
  const float L     = 1.0f - w2sq - w4sq;
  const float gamma = (w3 * w3) / 1000.0f;
  const float delta = fmaf(w3, b3, b3);
  const float s1_0 = x[1], s3_0 = x[3];

  if (rows == 2047) {
    f2 W;  W.x = x[0];  W.y = x[2];      // (u, v), lane-invariant
    f2 C1; C1.x = gamma; C1.y = -gamma;
    f2 C2; C2.x = L;     C2.y = 1.0f;
    f2 C3; C3.x = delta; C3.y = -delta;

    float G = W.x;  // Σ u_t for t=0..R0 (starts u_0)

#pragma unroll 1
    for (int b = 0; b < 4; ++b) {  // 4 blocks x 512 steps
      float PU = 0.0f, PV = 0.0f;
      // ---- serial phase: 512 steps, park at j%8==0 into lane j/8 ----
#pragma unroll
      for (int jj = 0; jj < 64; ++jj) {
        f2 FG;
        STEP(W, FG)                     // step 512b+8jj -> u_{512b+8jj+1}
        const bool park = (lane == jj); // jj literal -> inline-const cmp
        PU = park ? W.x : PU;
        PV = park ? W.y : PV;
#pragma unroll
        for (int t = 1; t < 8; ++t) { f2 FG2; STEP(W, FG2) }
      }
      // ---- parallel recovery: lane l owns rows 512b+8l .. +7 ----
      float U[8], V[8];
      f2 R; R.x = PU; R.y = PV;
      U[0] = PU; V[0] = PV;
#pragma unroll
      for (int t = 1; t < 8; ++t) { f2 FG; STEP(R, FG) U[t] = R.x; V[t] = R.y; }
      // ---- s1/s3 from prefix sums of u (R10-proven scan family) ----
      float Q = U[0];
#pragma unroll
      for (int t = 1; t < 8; ++t) Q += U[t];
      const float S = wave_incl_scan(Q);
      float T = G + (S - Q);  // Σ u_t through index 512b+8l
      G += __shfl(S, 63);
      // ---- assemble 8 rows = 40 floats, store as 10 dwordx4 ----
      float flat[40];
#pragma unroll
      for (int t = 0; t < 8; ++t) {
        flat[5 * t + 0] = U[t];
        flat[5 * t + 1] = fmaf(w2sq, T, s1_0);
        flat[5 * t + 2] = V[t];
        flat[5 * t + 3] = fmaf(w4sq, T, s3_0);
        flat[5 * t + 4] = 0.0f;  // col 4 (d_out re-poisoned 0xAA)
        T += U[t];
      }
      float4* __restrict__ q4 = (float4*)(out + 2560 * b + 40 * lane);
      if (b < 3 || lane < 63) {
#pragma unroll
        for (int k = 0; k < 10; ++k)
          q4[k] = make_float4(flat[4*k], flat[4*k+1], flat[4*k+2], flat[4*k+3]);
      } else {
        // last lane of last block: rows 2040..2046 only (row 2047 is OOB)
#pragma unroll
        for (int k = 0; k < 8; ++k)
          q4[k] = make_float4(flat[4*k], flat[4*k+1], flat[4*k+2], flat[4*k+3]);
        ((float2*)(q4 + 8))[0] = make_float2(flat[32], flat[33]);
        ((float*)q4)[34] = flat[34];
      }
    }
  } else {
    // generic fallback: lane-0 scalar loop, proven FP sequence, all 5 cols
    if (lane == 0) {
      float u = x[0], v = x[2], s1 = s1_0, s3 = s3_0;
      const float mgamma = -gamma, mdelta = -delta;
      float* __restrict__ p = out;
#pragma unroll 4
      for (int i = 0; i < rows; ++i) {
        const float f = fmaf(gamma, v, L);
        const float g = fmaf(mgamma, u, 1.0f);
        s1 = fmaf(w2sq, u, s1);
        s3 = fmaf(w4sq, u, s3);
        u = fmaf(u, f, delta);
        v = fmaf(v, g, mdelta);
        p[0] = u; p[1] = s1; p[2] = v; p[3] = s3; p[4] = 0.0f;
        p += 5;
      }
    }
  }
}

extern "C" void kernel_launch(void* const* d_in, const int* in_sizes, int n_in,
                              void* d_out, int out_size, void* d_ws, size_t ws_size,
                              hipStream_t stream) {
  const float* x   = (const float*)d_in[0];
  const float* w2  = (const float*)d_in[1];
  const float* w3  = (const float*)d_in[2];
  const float* b3  = (const float*)d_in[3];
  const float* w4  = (const float*)d_in[4];
  const int*   n   = (const int*)d_in[5];
  float* out = (float*)d_out;
  sir_kernel<<<1, 64, 0, stream>>>(x, w2, w3, b3, w4, n, out);
}

// Round 15
// 79.593 us; speedup vs baseline: 1.6531x; 1.0062x over previous
//
#include <hip/hip_runtime.h>

// SIR recurrence, R13: pure serial wave + offloaded parallel recovery.
// Law (R1-R12): solo wave = ~5.1 cyc per emitted instr, in-order, deps
// irrelevant; kernel ~= F(~10us fixed) + instr*5.1cyc. R12 serial = 4864
// instr (cndmask parking) + ~400 recovery on the critical wave.
// R13: (a) parking -> 1 ds_write_b64 per 16 steps (LDS checkpoints,
// immediate offsets after unroll): serial ~= 4096 pk_fma + 128 ds + loop.
// (b) 2nd wave sleeps through the serial phase, then BOTH waves recover:
// each of 128 lanes re-applies 16 steps from its checkpoint (bitwise-
// identical pk_fma), rebuilds s1/s3 via the R10-proven DPP scan (+ one
// cross-wave total via LDS), stores 16 rows as 20 dwordx4 (zeros packed).
//
//   step: FG = pk_fma((γ,-γ),(u,v) swapped,(L,1)); W = pk_fma(W,FG,(δ,-δ))
//   s1 at row r = fma(w2sq, T_r, s1_0), T_r = Σ_{j=0..r} W_j.x

typedef float f2 __attribute__((ext_vector_type(2)));

#define STEP(Wv, FGv)                                                    \
  asm("v_pk_fma_f32 %0, %1, %2, %3 op_sel:[0,1,0] op_sel_hi:[1,0,1]"     \
      : "=v"(FGv) : "v"(C1), "v"(Wv), "v"(C2));                          \
  asm("v_pk_fma_f32 %0, %0, %1, %2" : "+v"(Wv) : "v"(FGv), "v"(C3));

template <int CTRL, int RMASK>
__device__ __forceinline__ float dpp0(float x) {
  return __int_as_float(__builtin_amdgcn_update_dpp(
      0, __float_as_int(x), CTRL, RMASK, 0xf, false));
}

// canonical GCN wave64 inclusive prefix-sum: 6 DPP adds (proven R10-R12)
__device__ __forceinline__ float wave_incl_scan(float x) {
  x += dpp0<0x111, 0xf>(x);  // row_shr:1
  x += dpp0<0x112, 0xf>(x);  // row_shr:2
  x += dpp0<0x114, 0xf>(x);  // row_shr:4
  x += dpp0<0x118, 0xf>(x);  // row_shr:8
  x += dpp0<0x142, 0xa>(x);  // row_bcast:15 -> rows 1,3
  x += dpp0<0x143, 0xc>(x);  // row_bcast:31 -> rows 2,3
  return x;
}

__global__ __launch_bounds__(128) void sir_kernel(
    const float* __restrict__ x, const float* __restrict__ w2p,
    const float* __restrict__ w3p, const float* __restrict__ b3p,
    const float* __restrict__ w4p, const int* __restrict__ np,
    float* __restrict__ out) {
  const int tid = threadIdx.x;  // 2 waves of 64
  const int n = *np;
  const int rows = n - 1;

  const float w2 = *w2p, w3 = *w3p, b3 = *b3p, w4 = *w4p;
  const float w2sq  = w2 * w2;
  const float w4sq  = w4 * w4;
  const float L     = 1.0f - w2sq - w4sq;
  const float gamma = (w3 * w3) / 1000.0f;
  const float delta = fmaf(w3, b3, b3);
  const float s1_0 = x[1], s3_0 = x[3];

  f2 C1; C1.x = gamma; C1.y = -gamma;
  f2 C2; C2.x = L;     C2.y = 1.0f;
  f2 C3; C3.x = delta; C3.y = -delta;

  if (rows == 2047) {
    // ck[c][lane] = state W_{16c} (c=0 is the initial state); 64 KB
    __shared__ f2 ck[128][64];
    __shared__ float tot;  // wave-0 scan total for the cross-wave prefix

    if (tid < 64) {
      // ---- serial phase (wave 0; lane-invariant; wave 1 sleeps) ----
      f2 W; W.x = x[0]; W.y = x[2];
#pragma unroll 1
      for (int b = 0; b < 8; ++b) {
#pragma unroll
        for (int i = 0; i < 16; ++i) {
          ck[b * 16 + i][tid] = W;  // 1 ds_write_b64, imm offset i*512
#pragma unroll
          for (int t = 0; t < 16; ++t) { f2 FG; STEP(W, FG) }
        }
      }
    }
    __syncthreads();

    // ---- parallel recovery: lane g owns checkpoint g -> rows 16g..16g+15
    const int g = tid;
    f2 R = ck[g][g & 63];
    float U[17], V[17];
    U[0] = R.x; V[0] = R.y;
#pragma unroll
    for (int t = 1; t <= 16; ++t) { f2 FG; STEP(R, FG) U[t] = R.x; V[t] = R.y; }

    // per-lane u-sum over W_{16g..16g+15} (excl U[16])
    float Q = U[0];
#pragma unroll
    for (int t = 1; t < 16; ++t) Q += U[t];
    const float S = wave_incl_scan(Q);
    if (tid == 63) tot = S;
    __syncthreads();
    float T = (S - Q) + (tid >= 64 ? tot : 0.0f);  // global exclusive prefix

    // ---- assemble + store 16 rows as 2 groups of 8 (40 floats each) ----
#pragma unroll
    for (int h = 0; h < 2; ++h) {
      float flat[40];
#pragma unroll
      for (int t8 = 0; t8 < 8; ++t8) {
        const int t = 8 * h + t8;
        T += U[t];  // T_incl at row 16g+t
        flat[5 * t8 + 0] = U[t + 1];               // col0: W_{r+1}.x
        flat[5 * t8 + 1] = fmaf(w2sq, T, s1_0);    // col1
        flat[5 * t8 + 2] = V[t + 1];               // col2
        flat[5 * t8 + 3] = fmaf(w4sq, T, s3_0);    // col3
        flat[5 * t8 + 4] = 0.0f;                   // col4 (0xAA-poisoned)
      }
      float4* __restrict__ q4 = (float4*)(out + 80 * g + 40 * h);
      if (g < 127 || h == 0) {
#pragma unroll
        for (int k = 0; k < 10; ++k)
          q4[k] = make_float4(flat[4*k], flat[4*k+1], flat[4*k+2], flat[4*k+3]);
      } else {
        // last lane, second group: rows 2040..2046 only (row 2047 is OOB)
#pragma unroll
        for (int k = 0; k < 8; ++k)
          q4[k] = make_float4(flat[4*k], flat[4*k+1], flat[4*k+2], flat[4*k+3]);
        ((float2*)(q4 + 8))[0] = make_float2(flat[32], flat[33]);
        ((float*)q4)[34] = flat[34];
      }
    }
  } else {
    // generic fallback: lane-0 scalar loop, proven FP sequence, all 5 cols
    if (tid == 0) {
      float u = x[0], v = x[2], s1 = s1_0, s3 = s3_0;
      const float mgamma = -gamma, mdelta = -delta;
      float* __restrict__ p = out;
#pragma unroll 4
      for (int i = 0; i < rows; ++i) {
        const float f = fmaf(gamma, v, L);
        const float gg = fmaf(mgamma, u, 1.0f);
        s1 = fmaf(w2sq, u, s1);
        s3 = fmaf(w4sq, u, s3);
        u = fmaf(u, f, delta);
        v = fmaf(v, gg, mdelta);
        p[0] = u; p[1] = s1; p[2] = v; p[3] = s3; p[4] = 0.0f;
        p += 5;
      }
    }
  }
}

extern "C" void kernel_launch(void* const* d_in, const int* in_sizes, int n_in,
                              void* d_out, int out_size, void* d_ws, size_t ws_size,
                              hipStream_t stream) {
  const float* x   = (const float*)d_in[0];
  const float* w2  = (const float*)d_in[1];
  const float* w3  = (const float*)d_in[2];
  const float* b3  = (const float*)d_in[3];
  const float* w4  = (const float*)d_in[4];
  const int*   n   = (const int*)d_in[5];
  float* out = (float*)d_out;
  sir_kernel<<<1, 128, 0, stream>>>(x, w2, w3, b3, w4, n, out);
}